// Round 16
// baseline (3792.228 us; speedup 1.0000x reference)
//
#include <hip/hip_runtime.h>
#include <stdint.h>

// ---------- types ----------
typedef short short8v __attribute__((ext_vector_type(8)));
typedef float f32x4  __attribute__((ext_vector_type(4)));
typedef unsigned long long u64;

__device__ inline uint16_t f2bf(float f){
  uint32_t u = __float_as_uint(f);
  uint32_t r = (u + 0x7fffu + ((u >> 16) & 1u)) >> 16;
  return (uint16_t)r;
}
__device__ inline float bf2f(uint16_t h){
  return __uint_as_float(((uint32_t)h) << 16);
}

// ---------- f32 -> bf16 conversion (vectorized) ----------
__global__ void cvt_f32_bf16(const float* __restrict__ src, uint16_t* __restrict__ dst, int n4){
  int i = blockIdx.x * blockDim.x + threadIdx.x;
  int stride = gridDim.x * blockDim.x;
  for (; i < n4; i += stride){
    float4 v = ((const float4*)src)[i];
    uint64_t p = (uint64_t)f2bf(v.x)
               | ((uint64_t)f2bf(v.y) << 16)
               | ((uint64_t)f2bf(v.z) << 32)
               | ((uint64_t)f2bf(v.w) << 48);
    ((uint64_t*)dst)[i] = p;
  }
}

// ---------- bf16 GEMM: C[m,n] = sum_k A[m,k] * Bw[n,k] + bias[n]  (C bf16) ----------
#define GL2LDS(g, l) __builtin_amdgcn_global_load_lds((const __attribute__((address_space(1))) unsigned int*)(g), (__attribute__((address_space(3))) unsigned int*)(l), 16, 0, 0)

__global__ __launch_bounds__(256) void gemm_bt_bias(
    const uint16_t* __restrict__ A, const uint16_t* __restrict__ Bw,
    const float* __restrict__ bias, uint16_t* __restrict__ C,
    int M, int N, int K)
{
  __shared__ uint16_t As[128 * 64];
  __shared__ uint16_t Bs[128 * 64];
  const int tid  = threadIdx.x;
  const int lane = tid & 63, wid = tid >> 6;
  const int n0 = blockIdx.x * 128, m0 = blockIdx.y * 128;
  const int wrow = (wid & 1) * 64, wcol = (wid >> 1) * 64;
  const int l15 = lane & 15, l4 = lane >> 4;
  const int srow = lane >> 3, scol = (lane & 7) * 8;
  const size_t Ks = (size_t)K;

  f32x4 acc[4][4] = {};

  for (int kt = 0; kt < K; kt += 64){
    __syncthreads();
    const uint16_t* gA = A  + (size_t)m0 * Ks + kt;
    const uint16_t* gB = Bw + (size_t)n0 * Ks + kt;
    #pragma unroll
    for (int i = 0; i < 4; ++i){
      int rb = wid * 32 + i * 8;
      GL2LDS(gA + (size_t)(rb + srow) * Ks + scol, &As[rb * 64]);
      GL2LDS(gB + (size_t)(rb + srow) * Ks + scol, &Bs[rb * 64]);
    }
    __syncthreads();
    #pragma unroll
    for (int kk = 0; kk < 2; ++kk){
      short8v a[4], b[4];
      int koff = kk * 32 + l4 * 8;
      #pragma unroll
      for (int mt = 0; mt < 4; ++mt) a[mt] = *(const short8v*)&As[(wrow + mt*16 + l15) * 64 + koff];
      #pragma unroll
      for (int nt = 0; nt < 4; ++nt) b[nt] = *(const short8v*)&Bs[(wcol + nt*16 + l15) * 64 + koff];
      #pragma unroll
      for (int mt = 0; mt < 4; ++mt)
        #pragma unroll
        for (int nt = 0; nt < 4; ++nt)
          acc[mt][nt] = __builtin_amdgcn_mfma_f32_16x16x32_bf16(a[mt], b[nt], acc[mt][nt], 0, 0, 0);
    }
  }
  #pragma unroll
  for (int mt = 0; mt < 4; ++mt)
    #pragma unroll
    for (int nt = 0; nt < 4; ++nt){
      int col = n0 + wcol + nt * 16 + l15;
      float bv = bias[col];
      int rbase = m0 + wrow + mt * 16 + l4 * 4;
      #pragma unroll
      for (int j = 0; j < 4; ++j)
        C[(size_t)(rbase + j) * (size_t)N + col] = f2bf(acc[mt][nt][j] + bv);
    }
}

// LDS reduce index, stride 40 f32 (=10 4-bank granules, same verified XOR
// family as r10's stride-72: f32x4 writes land 8 lanes per granule slot,
// conflict-free; max offset m^((c&7)<<2) = 31 < 40).
__device__ inline int ridx(int w, int c, int m){
  return (w * 48 + c) * 40 + (m ^ ((c & 7) << 2));
}

// 16B MALL-direct load (bypass L1+L2) — proven r4/r10
#define HLOAD(dst, addr) \
  asm volatile("global_load_dwordx4 %0, %1, off sc0 sc1" : "=v"(dst) : "v"(addr) : "memory")
// plain cached 2B load (xp), participates in the counted window
#define XPLOAD2(dst, addr) \
  asm volatile("global_load_ushort %0, %1, off" : "=v"(dst) : "v"(addr) : "memory")
// write-through 2B store (h)
#define HSTORE2(addr, val) \
  asm volatile("global_store_short %0, %1, off sc0 sc1" :: "v"(addr), "v"(val) : "memory")
#define OSTORE2(addr, val) \
  asm volatile("global_store_short %0, %1, off nt" :: "v"(addr), "v"(val) : "memory")
#define OSTORE4(addr, val) \
  asm volatile("global_store_dword %0, %1, off nt" :: "v"(addr), "v"(val) : "memory")
#define WAITVM(n) do { asm volatile("s_waitcnt vmcnt(" #n ")" ::: "memory"); \
                       __builtin_amdgcn_sched_barrier(0); } while (0)

// LDS half-barrier: 4 waves of one direction-half arrive (lane0 adds), all
// lanes spin. Monotonic target 4*(s+1) per step — no reset races.
__device__ __forceinline__ void half_bar(unsigned* c, unsigned tgt, int lane){
  if (lane == 0)
    __hip_atomic_fetch_add(c, 1u, __ATOMIC_RELEASE, __HIP_MEMORY_SCOPE_WORKGROUP);
  while (__hip_atomic_load(c, __ATOMIC_ACQUIRE, __HIP_MEMORY_SCOPE_WORKGROUP) < tgt) {}
}

// ---------- persistent bidirectional GRU layer, dir-paired 2-D decomposition ----------
// grid = 256 blocks x 512 threads: grp = bid>>6 (rows grp*16..+15), cb = bid&63
// (cols cb*16..+15). Waves 0-3 = fwd half, waves 4-7 = bwd half — two
// INDEPENDENT sync domains on one CU; when one half stalls on its poll/load
// round trips, the other half's waves compute. No block barrier in the loop:
// per-wave subset polling (wave kw polls its 16 producers) + LDS half-barriers
// (HB1: partials->reduce; HB2: red-WAR + h-commit before flag).
// h exchange per half: [2 par][2 dir][4 grp][64 cb] 512B chunks
// ([16 rows][16 cols] bf16), sc0sc1 write-through + ack + flag (r10-proven).
__global__ __launch_bounds__(512, 2) void gru_layer(
    const uint16_t* __restrict__ xp,   // (T,B,3H) bf16 (bias already added)
    const uint16_t* __restrict__ U,    // (3H, H) bf16, rows: Ur | Uz | Un
    const float* __restrict__ bn,      // (H)
    char* __restrict__ hbuf,           // [2 par][2 dir][4 grp][64 cb] * 512B
    uint16_t* __restrict__ out_bf,     // (T,B,2H) bf16 or null
    float* __restrict__ out_f32,       // (T,B,2H) f32 or null
    float* __restrict__ hid,           // 2 slots of (64,1024) f32: fwd then bwd
    unsigned* __restrict__ flags)      // [2 dir][4 grp][64] packed u32
{
  __shared__ float red[2][7680];       // per half: 4*48*40 f32 (30720B)
  __shared__ unsigned hb1[2], hb2[2];
  const int tid  = threadIdx.x;
  const int lane = tid & 63, wid = tid >> 6;
  const int d    = wid >> 2;           // direction half 0/1
  const int kw   = wid & 3;            // K-split wave within half
  const int grp  = blockIdx.x >> 6;    // 0..3
  const int cb   = blockIdx.x & 63;
  const int c0   = cb * 16;
  const int brow0 = grp * 16;
  const int l15 = lane & 15, l4 = lane >> 4;
  const int tid256 = tid & 255;
  const int gm = tid256 >> 4, c16 = tid256 & 15;   // gate: row gm, col c16
  unsigned* myflags = flags + (d * 4 + grp) * 64;

  if (tid < 2){ hb1[tid] = 0; hb2[tid] = 0; }
  __syncthreads();                     // once, pre-loop

  // register-resident B fragments (U weights), reused for all 256 steps
  short8v bfr[3][8];
  #pragma unroll
  for (int g = 0; g < 3; ++g)
    #pragma unroll
    for (int k32 = 0; k32 < 8; ++k32){
      int row = g * 1024 + c0 + l15;
      int k   = kw * 256 + k32 * 32 + l4 * 8;
      bfr[g][k32] = *(const short8v*)&U[(size_t)row * 1024 + k];
    }

  float hold = 0.f;
  const float bnv = bn[c0 + c16];

  // consumer h geometry: chunk cb' = kw*16 + k32*2 + (l4>>1); within chunk:
  // row l15 (stride 32B), col-octet (l4&1)*16B  ->  one dwordx4 per lane,
  // each instruction reads 1KB contiguous (2 adjacent 512B chunks).
  const size_t hoff = (size_t)(kw * 16 + (l4 >> 1)) * 512 + (size_t)(l4 & 1) * 16 + (size_t)l15 * 32;

  for (int s = 0; s < 256; ++s){
    const int par = s & 1;
    const int t = d ? (255 - s) : s;
    const size_t xb2 = ((size_t)t * 64 + brow0 + gm) * 3072 + c0 + c16;

    f32x4 acc[3] = {};
    unsigned pxr, pxz, pxn;
    if (s > 0){
      // ---- per-wave poll: the 16 producers of MY chunks ----
      {
        const unsigned tgt = (unsigned)s;
        const unsigned* fp = myflags + kw * 16 + l15;
        int spins = 0;
        for (;;){
          unsigned v;
          asm volatile("global_load_dword %0, %1, off sc0 sc1" : "=v"(v) : "v"(fp) : "memory");
          asm volatile("s_waitcnt vmcnt(0)" ::: "memory");
          if (__all((int)(v >= tgt))) break;
          __builtin_amdgcn_s_sleep(1);
          if (((++spins) & 1023) == 0)
            __builtin_amdgcn_fence(__ATOMIC_ACQUIRE, "agent");   // deadlock safety valve
        }
      }

      const char* hgbase = hbuf + (size_t)(((par * 2 + d) * 4 + grp) * 64) * 512;

      // ---- K-window: 3 chunks ahead (1 load each); xp folded in at kk==4 ----
      short8v hc[8];
      #pragma unroll
      for (int c = 0; c < 3; ++c)
        HLOAD(hc[c], hgbase + hoff + (size_t)c * 1024);

      #pragma unroll
      for (int kk = 0; kk < 8; ++kk){
        if (kk < 5)
          HLOAD(hc[kk + 3], hgbase + hoff + (size_t)(kk + 3) * 1024);
        if (kk == 4){   // xp loads issued after ALL h loads (in-order retire)
          XPLOAD2(pxr, &xp[xb2]);
          XPLOAD2(pxz, &xp[xb2 + 1024]);
          XPLOAD2(pxn, &xp[xb2 + 2048]);
        }
        if      (kk <  4) WAITVM(3);
        else if (kk == 4) WAITVM(6);
        else if (kk == 5) WAITVM(5);
        else if (kk == 6) WAITVM(4);
        else              WAITVM(3);
        #pragma unroll
        for (int g = 0; g < 3; ++g)
          acc[g] = __builtin_amdgcn_mfma_f32_16x16x32_bf16(hc[kk], bfr[g][kk], acc[g], 0, 0, 0);
      }
    } else {
      pxr = xp[xb2];
      pxz = xp[xb2 + 1024];
      pxn = xp[xb2 + 2048];
    }

    // partial sums to LDS (per half, stride-40 swizzled, conflict-free writes)
    #pragma unroll
    for (int g = 0; g < 3; ++g)
      *(f32x4*)&red[d][ridx(kw, g * 16 + l15, l4 * 4)] = acc[g];
    half_bar(&hb1[d], 4u * (unsigned)(s + 1), lane);   // partials ready

    // reduce over the half's 4 waves; thread -> (row gm, col c16)
    float ra = 0.f, za = 0.f, na = 0.f;
    #pragma unroll
    for (int w = 0; w < 4; ++w){
      ra += red[d][ridx(w,      c16, gm)];
      za += red[d][ridx(w, 16 + c16, gm)];
      na += red[d][ridx(w, 32 + c16, gm)];
    }

    WAITVM(0);                             // xp in registers (queue empty)
    float xr = bf2f((uint16_t)pxr);
    float xz = bf2f((uint16_t)pxz);
    float xn = bf2f((uint16_t)pxn);
    float r = 1.f / (1.f + __expf(-(xr + ra)));
    float z = 1.f / (1.f + __expf(-(xz + za)));
    float n = tanhf(xn + r * (na + bnv));
    float hn = (1.f - z) * n + z * hold;
    hold = hn;
    unsigned hv = f2bf(hn);

    if (s < 255){
      // own-chunk h store: 512B contiguous per half, write-through to MALL
      char* hw = hbuf + (size_t)((((par ^ 1) * 2 + d) * 4 + grp) * 64 + cb) * 512
               + (size_t)gm * 32 + (size_t)c16 * 2;
      HSTORE2(hw, hv);
      WAITVM(0);                           // h committed (this wave)
      // HB2: all 4 waves committed + red reads done (covers WAR for next step)
      half_bar(&hb2[d], 4u * (unsigned)(s + 1), lane);
      if (tid256 == 0)
        __hip_atomic_store(&myflags[cb], (unsigned)(s + 1), __ATOMIC_RELAXED, __HIP_MEMORY_SCOPE_AGENT);
      __builtin_amdgcn_sched_barrier(0);
    }

    // out store AFTER flag (drains in next poll)
    {
      size_t obase = ((size_t)t * 64 + brow0 + gm) * 2048 + (size_t)d * 1024 + c0 + c16;
      if (out_bf) OSTORE2(&out_bf[obase], hv);
      else        OSTORE4(&out_f32[obase], __float_as_uint(hn));
      if (s == 255)
        hid[((size_t)d * 64 + brow0 + gm) * 1024 + c0 + c16] = hn;
    }
  }
}

// ---------- host ----------
extern "C" void kernel_launch(void* const* d_in, const int* in_sizes, int n_in,
                              void* d_out, int out_size, void* d_ws, size_t ws_size,
                              hipStream_t stream) {
  const float* x   = (const float*)d_in[0];
  const float* W0  = (const float*)d_in[1];
  const float* b0  = (const float*)d_in[2];
  const float* Ur0 = (const float*)d_in[3];
  const float* Uz0 = (const float*)d_in[4];
  const float* Un0 = (const float*)d_in[5];
  const float* bn0 = (const float*)d_in[6];
  const float* W1  = (const float*)d_in[7];
  const float* b1  = (const float*)d_in[8];
  const float* Ur1 = (const float*)d_in[9];
  const float* Uz1 = (const float*)d_in[10];
  const float* Un1 = (const float*)d_in[11];
  const float* bn1 = (const float*)d_in[12];
  float* out = (float*)d_out;

  char* base = (char*)d_ws;
  unsigned* ctr0 = (unsigned*)base;                  // layer0 flags (2KB)
  unsigned* ctr1 = (unsigned*)(base + 4096);         // layer1 flags
  uint16_t* xb    = (uint16_t*)(base + 8192);
  uint16_t* w0b   = xb    + (size_t)16384 * 1024;
  uint16_t* u0b   = w0b   + (size_t)3072 * 1024;
  uint16_t* w1b   = u0b   + (size_t)3072 * 1024;
  uint16_t* u1b   = w1b   + (size_t)3072 * 2048;
  uint16_t* xp    = u1b   + (size_t)3072 * 1024;
  uint16_t* out0b = xp    + (size_t)16384 * 3072;
  char*     hbuf  = (char*)(out0b + (size_t)16384 * 2048);   // 512 KB chunks

  hipMemsetAsync(d_ws, 0, 8192, stream);

  auto cvt = [&](const float* s, uint16_t* d, size_t n){
    int n4 = (int)(n / 4);
    int grid = (n4 + 255) / 256; if (grid > 2048) grid = 2048;
    hipLaunchKernelGGL(cvt_f32_bf16, dim3(grid), dim3(256), 0, stream, s, d, n4);
  };
  cvt(x,   xb,  (size_t)16384 * 1024);
  cvt(W0,  w0b, (size_t)3072 * 1024);
  cvt(Ur0, u0b + 0 * (size_t)1024 * 1024, (size_t)1024 * 1024);
  cvt(Uz0, u0b + 1 * (size_t)1024 * 1024, (size_t)1024 * 1024);
  cvt(Un0, u0b + 2 * (size_t)1024 * 1024, (size_t)1024 * 1024);
  cvt(W1,  w1b, (size_t)3072 * 2048);
  cvt(Ur1, u1b + 0 * (size_t)1024 * 1024, (size_t)1024 * 1024);
  cvt(Uz1, u1b + 1 * (size_t)1024 * 1024, (size_t)1024 * 1024);
  cvt(Un1, u1b + 2 * (size_t)1024 * 1024, (size_t)1024 * 1024);

  // layer 0: xp0 = x @ W0^T + b0
  hipLaunchKernelGGL(gemm_bt_bias, dim3(24, 128), dim3(256), 0, stream,
                     xb, w0b, b0, xp, 16384, 3072, 1024);
  // layer 0 recurrence -> out0b (bf16), hidden slots 0,1
  hipLaunchKernelGGL(gru_layer, dim3(256), dim3(512), 0, stream,
                     xp, u0b, bn0, hbuf,
                     out0b, (float*)nullptr,
                     out + (size_t)33554432, ctr0);
  // layer 1: xp1 = out0 @ W1^T + b1
  hipLaunchKernelGGL(gemm_bt_bias, dim3(24, 128), dim3(256), 0, stream,
                     out0b, w1b, b1, xp, 16384, 3072, 2048);
  // layer 1 recurrence -> d_out (f32), hidden slots 2,3
  hipLaunchKernelGGL(gru_layer, dim3(256), dim3(512), 0, stream,
                     xp, u1b, bn1, hbuf,
                     (uint16_t*)nullptr, out,
                     out + (size_t)33554432 + (size_t)2 * 64 * 1024, ctr1);
}

// Round 17
// 3457.508 us; speedup vs baseline: 1.0968x; 1.0968x over previous
//
#include <hip/hip_runtime.h>
#include <stdint.h>

// ---------- types ----------
typedef short short8v __attribute__((ext_vector_type(8)));
typedef float f32x4  __attribute__((ext_vector_type(4)));
typedef unsigned int u32x4 __attribute__((ext_vector_type(4)));
typedef unsigned long long u64;

__device__ inline uint16_t f2bf(float f){
  uint32_t u = __float_as_uint(f);
  uint32_t r = (u + 0x7fffu + ((u >> 16) & 1u)) >> 16;
  return (uint16_t)r;
}
__device__ inline float bf2f(uint16_t h){
  return __uint_as_float(((uint32_t)h) << 16);
}

// ---------- f32 -> bf16 conversion (vectorized) ----------
__global__ void cvt_f32_bf16(const float* __restrict__ src, uint16_t* __restrict__ dst, int n4){
  int i = blockIdx.x * blockDim.x + threadIdx.x;
  int stride = gridDim.x * blockDim.x;
  for (; i < n4; i += stride){
    float4 v = ((const float4*)src)[i];
    uint64_t p = (uint64_t)f2bf(v.x)
               | ((uint64_t)f2bf(v.y) << 16)
               | ((uint64_t)f2bf(v.z) << 32)
               | ((uint64_t)f2bf(v.w) << 48);
    ((uint64_t*)dst)[i] = p;
  }
}

// ---------- bf16 GEMM: C[m,n] = sum_k A[m,k] * Bw[n,k] + bias[n]  (C bf16) ----------
#define GL2LDS(g, l) __builtin_amdgcn_global_load_lds((const __attribute__((address_space(1))) unsigned int*)(g), (__attribute__((address_space(3))) unsigned int*)(l), 16, 0, 0)

__global__ __launch_bounds__(256) void gemm_bt_bias(
    const uint16_t* __restrict__ A, const uint16_t* __restrict__ Bw,
    const float* __restrict__ bias, uint16_t* __restrict__ C,
    int M, int N, int K)
{
  __shared__ uint16_t As[128 * 64];
  __shared__ uint16_t Bs[128 * 64];
  const int tid  = threadIdx.x;
  const int lane = tid & 63, wid = tid >> 6;
  const int n0 = blockIdx.x * 128, m0 = blockIdx.y * 128;
  const int wrow = (wid & 1) * 64, wcol = (wid >> 1) * 64;
  const int l15 = lane & 15, l4 = lane >> 4;
  const int srow = lane >> 3, scol = (lane & 7) * 8;
  const size_t Ks = (size_t)K;

  f32x4 acc[4][4] = {};

  for (int kt = 0; kt < K; kt += 64){
    __syncthreads();
    const uint16_t* gA = A  + (size_t)m0 * Ks + kt;
    const uint16_t* gB = Bw + (size_t)n0 * Ks + kt;
    #pragma unroll
    for (int i = 0; i < 4; ++i){
      int rb = wid * 32 + i * 8;
      GL2LDS(gA + (size_t)(rb + srow) * Ks + scol, &As[rb * 64]);
      GL2LDS(gB + (size_t)(rb + srow) * Ks + scol, &Bs[rb * 64]);
    }
    __syncthreads();
    #pragma unroll
    for (int kk = 0; kk < 2; ++kk){
      short8v a[4], b[4];
      int koff = kk * 32 + l4 * 8;
      #pragma unroll
      for (int mt = 0; mt < 4; ++mt) a[mt] = *(const short8v*)&As[(wrow + mt*16 + l15) * 64 + koff];
      #pragma unroll
      for (int nt = 0; nt < 4; ++nt) b[nt] = *(const short8v*)&Bs[(wcol + nt*16 + l15) * 64 + koff];
      #pragma unroll
      for (int mt = 0; mt < 4; ++mt)
        #pragma unroll
        for (int nt = 0; nt < 4; ++nt)
          acc[mt][nt] = __builtin_amdgcn_mfma_f32_16x16x32_bf16(a[mt], b[nt], acc[mt][nt], 0, 0, 0);
    }
  }
  #pragma unroll
  for (int mt = 0; mt < 4; ++mt)
    #pragma unroll
    for (int nt = 0; nt < 4; ++nt){
      int col = n0 + wcol + nt * 16 + l15;
      float bv = bias[col];
      int rbase = m0 + wrow + mt * 16 + l4 * 4;
      #pragma unroll
      for (int j = 0; j < 4; ++j)
        C[(size_t)(rbase + j) * (size_t)N + col] = f2bf(acc[mt][nt][j] + bv);
    }
}

// LDS reduce index, stride 40 f32 (=10 4-bank granules; same verified XOR
// family as r10's stride-72: f32x4 writes land 8 lanes/granule, conflict-free;
// max m^((c&7)<<2) = 31 < 40).
__device__ inline int ridx(int w, int c, int m){
  return (w * 48 + c) * 40 + (m ^ ((c & 7) << 2));
}

// 16B MALL-direct load (bypass L1+L2) — proven r4/r10
#define HLOAD(dst, addr) \
  asm volatile("global_load_dwordx4 %0, %1, off sc0 sc1" : "=v"(dst) : "v"(addr) : "memory")
// plain cached 2B load (xp), participates in the counted window
#define XPLOAD2(dst, addr) \
  asm volatile("global_load_ushort %0, %1, off" : "=v"(dst) : "v"(addr) : "memory")
// write-through 2B store (h)
#define HSTORE2(addr, val) \
  asm volatile("global_store_short %0, %1, off sc0 sc1" :: "v"(addr), "v"(val) : "memory")
#define OSTORE2(addr, val) \
  asm volatile("global_store_short %0, %1, off nt" :: "v"(addr), "v"(val) : "memory")
#define OSTORE4(addr, val) \
  asm volatile("global_store_dword %0, %1, off nt" :: "v"(addr), "v"(val) : "memory")
#define WAITVM(n) do { asm volatile("s_waitcnt vmcnt(" #n ")" ::: "memory"); \
                       __builtin_amdgcn_sched_barrier(0); } while (0)

// ---------- persistent bidirectional GRU layer, 4-group 2-D decomposition ----------
// Batch rows independent across the recurrence -> 4 groups of 16 rows.
// grid = 512 blocks x 256 threads: dir = bid>>8, grp = (bid>>6)&3, cb = bid&63.
// 2 blocks/CU: co-resident blocks are (mostly) in DIFFERENT sync domains, so
// one block's poll/ack round trips hide under the other's stream/compute.
// Per-block protocol = r15-proven verbatim: wave0 subset-poll (s_sleep) +
// 2 syncthreads + sc0sc1 write-through h + ack + packed flag; counted-vmcnt
// K-window with xp folded in; stride-40 swizzled LDS reduce.
__global__ __launch_bounds__(256, 2) void gru_layer(
    const uint16_t* __restrict__ xp,   // (T,B,3H) bf16 (bias already added)
    const uint16_t* __restrict__ U,    // (3H, H) bf16, rows: Ur | Uz | Un
    const float* __restrict__ bn,      // (H)
    char* __restrict__ hbuf,           // [2 par][2 dir][4 grp][64 cb] * 512B
    uint16_t* __restrict__ out_bf,     // (T,B,2H) bf16 or null
    float* __restrict__ out_f32,       // (T,B,2H) f32 or null
    float* __restrict__ hid,           // 2 slots of (64,1024) f32: fwd then bwd
    unsigned* __restrict__ flags)      // [2 dir][4 grp][64] packed u32
{
  __shared__ float red[4 * 48 * 40];   // 30720 B
  const int tid  = threadIdx.x;
  const int lane = tid & 63, wid = tid >> 6;
  const int bid  = blockIdx.x;
  const int dir  = bid >> 8;
  const int grp  = (bid >> 6) & 3;
  const int dg   = dir * 4 + grp;      // sync-domain id 0..7
  const int cb   = bid & 63;
  const int c0   = cb * 16;
  const int brow0 = grp * 16;
  const int l15 = lane & 15, l4 = lane >> 4;
  const int gm = tid >> 4, c16 = tid & 15;   // gate: row gm (0..15), col c16
  unsigned* myflags = flags + dg * 64;

  // register-resident B fragments (U weights), reused for all 256 steps
  short8v bfr[3][8];
  #pragma unroll
  for (int g = 0; g < 3; ++g)
    #pragma unroll
    for (int k32 = 0; k32 < 8; ++k32){
      int row = g * 1024 + c0 + l15;
      int k   = wid * 256 + k32 * 32 + l4 * 8;
      bfr[g][k32] = *(const short8v*)&U[(size_t)row * 1024 + k];
    }

  float hold = 0.f;
  const float bnv = bn[c0 + c16];

  // consumer h geometry: wave wid needs cols wid*256..+255 = chunks
  // cb' = wid*16..+15 (each 512B = [16 rows][16 cols]). One dwordx4/lane,
  // each instruction covers 2 adjacent chunks (1KB contiguous):
  // chunk-pair c, lane -> chunk (l4>>1), row l15, col-octet (l4&1).
  const size_t hoff = (size_t)(wid * 16 + (l4 >> 1)) * 512 + (size_t)(l4 & 1) * 16 + (size_t)l15 * 32;

  for (int s = 0; s < 256; ++s){
    const int par = s & 1;
    const int t = dir ? (255 - s) : s;
    const size_t xb2 = ((size_t)t * 64 + brow0 + gm) * 3072 + c0 + c16;

    f32x4 acc[3] = {};
    unsigned pxr, pxz, pxn;
    if (s > 0){
      // ---- wave0 polls the 64 packed flags of MY domain (dwordx4) ----
      if (wid == 0){
        const unsigned tgt = (unsigned)s;
        const unsigned* fp = myflags + (lane & 15) * 4;
        int spins = 0;
        for (;;){
          u32x4 fv;
          asm volatile("global_load_dwordx4 %0, %1, off sc0 sc1" : "=v"(fv) : "v"(fp) : "memory");
          asm volatile("s_waitcnt vmcnt(0)" ::: "memory");
          if (__all((int)(fv.x >= tgt && fv.y >= tgt && fv.z >= tgt && fv.w >= tgt))) break;
          __builtin_amdgcn_s_sleep(1);
          if (((++spins) & 1023) == 0)
            __builtin_amdgcn_fence(__ATOMIC_ACQUIRE, "agent");   // deadlock safety valve
        }
      }
      __syncthreads();

      const char* hgbase = hbuf + (size_t)(((par * 2 + dir) * 4 + grp) * 64) * 512;

      // ---- K-window: 3 chunk-pairs ahead (1 load each); xp at kk==4 ----
      short8v hc[8];
      #pragma unroll
      for (int c = 0; c < 3; ++c)
        HLOAD(hc[c], hgbase + hoff + (size_t)c * 1024);

      #pragma unroll
      for (int kk = 0; kk < 8; ++kk){
        if (kk < 5)
          HLOAD(hc[kk + 3], hgbase + hoff + (size_t)(kk + 3) * 1024);
        if (kk == 4){   // xp loads issued after ALL h loads (in-order retire)
          XPLOAD2(pxr, &xp[xb2]);
          XPLOAD2(pxz, &xp[xb2 + 1024]);
          XPLOAD2(pxn, &xp[xb2 + 2048]);
        }
        if      (kk <  4) WAITVM(3);
        else if (kk == 4) WAITVM(6);
        else if (kk == 5) WAITVM(5);
        else if (kk == 6) WAITVM(4);
        else              WAITVM(3);
        #pragma unroll
        for (int g = 0; g < 3; ++g)
          acc[g] = __builtin_amdgcn_mfma_f32_16x16x32_bf16(hc[kk], bfr[g][kk], acc[g], 0, 0, 0);
      }
    } else {
      pxr = xp[xb2];
      pxz = xp[xb2 + 1024];
      pxn = xp[xb2 + 2048];
    }

    // partial sums to LDS (stride-40 swizzled, conflict-free writes)
    #pragma unroll
    for (int g = 0; g < 3; ++g)
      *(f32x4*)&red[ridx(wid, g * 16 + l15, l4 * 4)] = acc[g];
    __syncthreads();                       // sync1: all partials ready

    // reduce over 4 waves; thread -> (row gm, col c16)
    float ra = 0.f, za = 0.f, na = 0.f;
    #pragma unroll
    for (int w = 0; w < 4; ++w){
      ra += red[ridx(w,      c16, gm)];
      za += red[ridx(w, 16 + c16, gm)];
      na += red[ridx(w, 32 + c16, gm)];
    }

    WAITVM(0);                             // xp in registers (queue empty)
    float xr = bf2f((uint16_t)pxr);
    float xz = bf2f((uint16_t)pxz);
    float xn = bf2f((uint16_t)pxn);
    float r = 1.f / (1.f + __expf(-(xr + ra)));
    float z = 1.f / (1.f + __expf(-(xz + za)));
    float n = tanhf(xn + r * (na + bnv));
    float hn = (1.f - z) * n + z * hold;
    hold = hn;
    unsigned hv = f2bf(hn);

    if (s < 255){
      // own-chunk h store: 512B contiguous, write-through to MALL (proven)
      char* hw = hbuf + (size_t)((((par ^ 1) * 2 + dir) * 4 + grp) * 64 + cb) * 512
               + (size_t)gm * 32 + (size_t)c16 * 2;
      HSTORE2(hw, hv);
      WAITVM(0);                           // h committed (this wave)
      __syncthreads();                     // commit-sync: all waves' h + red reads done
      if (tid == 0)
        __hip_atomic_store(&myflags[cb], (unsigned)(s + 1), __ATOMIC_RELAXED, __HIP_MEMORY_SCOPE_AGENT);
      __builtin_amdgcn_sched_barrier(0);
    }

    // out store AFTER flag (drains in next poll)
    {
      size_t obase = ((size_t)t * 64 + brow0 + gm) * 2048 + (size_t)dir * 1024 + c0 + c16;
      if (out_bf) OSTORE2(&out_bf[obase], hv);
      else        OSTORE4(&out_f32[obase], __float_as_uint(hn));
      if (s == 255)
        hid[((size_t)dir * 64 + brow0 + gm) * 1024 + c0 + c16] = hn;
    }
  }
}

// ---------- host ----------
extern "C" void kernel_launch(void* const* d_in, const int* in_sizes, int n_in,
                              void* d_out, int out_size, void* d_ws, size_t ws_size,
                              hipStream_t stream) {
  const float* x   = (const float*)d_in[0];
  const float* W0  = (const float*)d_in[1];
  const float* b0  = (const float*)d_in[2];
  const float* Ur0 = (const float*)d_in[3];
  const float* Uz0 = (const float*)d_in[4];
  const float* Un0 = (const float*)d_in[5];
  const float* bn0 = (const float*)d_in[6];
  const float* W1  = (const float*)d_in[7];
  const float* b1  = (const float*)d_in[8];
  const float* Ur1 = (const float*)d_in[9];
  const float* Uz1 = (const float*)d_in[10];
  const float* Un1 = (const float*)d_in[11];
  const float* bn1 = (const float*)d_in[12];
  float* out = (float*)d_out;

  char* base = (char*)d_ws;
  unsigned* ctr0 = (unsigned*)base;                  // layer0 flags (2KB)
  unsigned* ctr1 = (unsigned*)(base + 4096);         // layer1 flags
  uint16_t* xb    = (uint16_t*)(base + 8192);
  uint16_t* w0b   = xb    + (size_t)16384 * 1024;
  uint16_t* u0b   = w0b   + (size_t)3072 * 1024;
  uint16_t* w1b   = u0b   + (size_t)3072 * 1024;
  uint16_t* u1b   = w1b   + (size_t)3072 * 2048;
  uint16_t* xp    = u1b   + (size_t)3072 * 1024;
  uint16_t* out0b = xp    + (size_t)16384 * 3072;
  char*     hbuf  = (char*)(out0b + (size_t)16384 * 2048);   // 512 KB chunks

  hipMemsetAsync(d_ws, 0, 8192, stream);

  auto cvt = [&](const float* s, uint16_t* d, size_t n){
    int n4 = (int)(n / 4);
    int grid = (n4 + 255) / 256; if (grid > 2048) grid = 2048;
    hipLaunchKernelGGL(cvt_f32_bf16, dim3(grid), dim3(256), 0, stream, s, d, n4);
  };
  cvt(x,   xb,  (size_t)16384 * 1024);
  cvt(W0,  w0b, (size_t)3072 * 1024);
  cvt(Ur0, u0b + 0 * (size_t)1024 * 1024, (size_t)1024 * 1024);
  cvt(Uz0, u0b + 1 * (size_t)1024 * 1024, (size_t)1024 * 1024);
  cvt(Un0, u0b + 2 * (size_t)1024 * 1024, (size_t)1024 * 1024);
  cvt(W1,  w1b, (size_t)3072 * 2048);
  cvt(Ur1, u1b + 0 * (size_t)1024 * 1024, (size_t)1024 * 1024);
  cvt(Uz1, u1b + 1 * (size_t)1024 * 1024, (size_t)1024 * 1024);
  cvt(Un1, u1b + 2 * (size_t)1024 * 1024, (size_t)1024 * 1024);

  // layer 0: xp0 = x @ W0^T + b0
  hipLaunchKernelGGL(gemm_bt_bias, dim3(24, 128), dim3(256), 0, stream,
                     xb, w0b, b0, xp, 16384, 3072, 1024);
  // layer 0 recurrence -> out0b (bf16), hidden slots 0,1
  hipLaunchKernelGGL(gru_layer, dim3(512), dim3(256), 0, stream,
                     xp, u0b, bn0, hbuf,
                     out0b, (float*)nullptr,
                     out + (size_t)33554432, ctr0);
  // layer 1: xp1 = out0 @ W1^T + b1
  hipLaunchKernelGGL(gemm_bt_bias, dim3(24, 128), dim3(256), 0, stream,
                     out0b, w1b, b1, xp, 16384, 3072, 2048);
  // layer 1 recurrence -> d_out (f32), hidden slots 2,3
  hipLaunchKernelGGL(gru_layer, dim3(512), dim3(256), 0, stream,
                     xp, u1b, bn1, hbuf,
                     (uint16_t*)nullptr, out,
                     out + (size_t)33554432 + (size_t)2 * 64 * 1024, ctr1);
}

// Round 18
// 2266.503 us; speedup vs baseline: 1.6732x; 1.5255x over previous
//
#include <hip/hip_runtime.h>
#include <stdint.h>

// ---------- types ----------
typedef short short8v __attribute__((ext_vector_type(8)));
typedef unsigned short u16x8 __attribute__((ext_vector_type(8)));
typedef float f32x4  __attribute__((ext_vector_type(4)));
typedef float f32x2  __attribute__((ext_vector_type(2)));
typedef unsigned long long u64;

__device__ inline uint16_t f2bf(float f){
  uint32_t u = __float_as_uint(f);
  uint32_t r = (u + 0x7fffu + ((u >> 16) & 1u)) >> 16;
  return (uint16_t)r;
}
__device__ inline float bf2f(uint16_t h){
  return __uint_as_float(((uint32_t)h) << 16);
}

// ---------- f32 -> bf16 conversion (vectorized) ----------
__global__ void cvt_f32_bf16(const float* __restrict__ src, uint16_t* __restrict__ dst, int n4){
  int i = blockIdx.x * blockDim.x + threadIdx.x;
  int stride = gridDim.x * blockDim.x;
  for (; i < n4; i += stride){
    float4 v = ((const float4*)src)[i];
    uint64_t p = (uint64_t)f2bf(v.x)
               | ((uint64_t)f2bf(v.y) << 16)
               | ((uint64_t)f2bf(v.z) << 32)
               | ((uint64_t)f2bf(v.w) << 48);
    ((uint64_t*)dst)[i] = p;
  }
}

// ---------- bf16 GEMM: C[m,n] = sum_k A[m,k] * Bw[n,k] + bias[n]  (C bf16) ----------
#define GL2LDS(g, l) __builtin_amdgcn_global_load_lds((const __attribute__((address_space(1))) unsigned int*)(g), (__attribute__((address_space(3))) unsigned int*)(l), 16, 0, 0)

__global__ __launch_bounds__(256) void gemm_bt_bias(
    const uint16_t* __restrict__ A, const uint16_t* __restrict__ Bw,
    const float* __restrict__ bias, uint16_t* __restrict__ C,
    int M, int N, int K)
{
  __shared__ uint16_t As[128 * 64];
  __shared__ uint16_t Bs[128 * 64];
  const int tid  = threadIdx.x;
  const int lane = tid & 63, wid = tid >> 6;
  const int n0 = blockIdx.x * 128, m0 = blockIdx.y * 128;
  const int wrow = (wid & 1) * 64, wcol = (wid >> 1) * 64;
  const int l15 = lane & 15, l4 = lane >> 4;
  const int srow = lane >> 3, scol = (lane & 7) * 8;
  const size_t Ks = (size_t)K;

  f32x4 acc[4][4] = {};

  for (int kt = 0; kt < K; kt += 64){
    __syncthreads();
    const uint16_t* gA = A  + (size_t)m0 * Ks + kt;
    const uint16_t* gB = Bw + (size_t)n0 * Ks + kt;
    #pragma unroll
    for (int i = 0; i < 4; ++i){
      int rb = wid * 32 + i * 8;
      GL2LDS(gA + (size_t)(rb + srow) * Ks + scol, &As[rb * 64]);
      GL2LDS(gB + (size_t)(rb + srow) * Ks + scol, &Bs[rb * 64]);
    }
    __syncthreads();
    #pragma unroll
    for (int kk = 0; kk < 2; ++kk){
      short8v a[4], b[4];
      int koff = kk * 32 + l4 * 8;
      #pragma unroll
      for (int mt = 0; mt < 4; ++mt) a[mt] = *(const short8v*)&As[(wrow + mt*16 + l15) * 64 + koff];
      #pragma unroll
      for (int nt = 0; nt < 4; ++nt) b[nt] = *(const short8v*)&Bs[(wcol + nt*16 + l15) * 64 + koff];
      #pragma unroll
      for (int mt = 0; mt < 4; ++mt)
        #pragma unroll
        for (int nt = 0; nt < 4; ++nt)
          acc[mt][nt] = __builtin_amdgcn_mfma_f32_16x16x32_bf16(a[mt], b[nt], acc[mt][nt], 0, 0, 0);
    }
  }
  #pragma unroll
  for (int mt = 0; mt < 4; ++mt)
    #pragma unroll
    for (int nt = 0; nt < 4; ++nt){
      int col = n0 + wcol + nt * 16 + l15;
      float bv = bias[col];
      int rbase = m0 + wrow + mt * 16 + l4 * 4;
      #pragma unroll
      for (int j = 0; j < 4; ++j)
        C[(size_t)(rbase + j) * (size_t)N + col] = f2bf(acc[mt][nt][j] + bv);
    }
}

// LDS reduce index, stride 72 f32 (verified r10: conflict-free f32x4 writes)
__device__ inline int ridx(int w, int c, int m){
  return (w * 48 + c) * 72 + (m ^ ((c & 7) << 2));
}

// 16B MALL-direct load (bypass L1+L2) — proven r4/r10
#define HLOAD(dst, addr) \
  asm volatile("global_load_dwordx4 %0, %1, off sc0 sc1" : "=v"(dst) : "v"(addr) : "memory")
// plain cached 4B load (xp), participates in the counted window
#define XPLOAD4(dst, addr) \
  asm volatile("global_load_dword %0, %1, off" : "=v"(dst) : "v"(addr) : "memory")
// write-through 4B store (h / sentinel), fire-and-forget
#define HSTORE4(addr, val) \
  asm volatile("global_store_dword %0, %1, off sc0 sc1" :: "v"(addr), "v"(val) : "memory")
#define OSTORE4(addr, val) \
  asm volatile("global_store_dword %0, %1, off nt" :: "v"(addr), "v"(val) : "memory")
#define OSTORE8(addr, val) \
  asm volatile("global_store_dwordx2 %0, %1, off nt" :: "v"(addr), "v"(val) : "memory")
#define WAITVM(n) do { asm volatile("s_waitcnt vmcnt(" #n ")" ::: "memory"); \
                       __builtin_amdgcn_sched_barrier(0); } while (0)

// ---------- persistent bidirectional GRU layer, self-certifying h ring ----------
// grid = 256 blocks x 256 threads (r15 geometry): dir = bid>>7, grp = (bid>>6)&1
// (32 batch rows), cb = bid&63 (16 h-cols). h lives in a 32-slot ring
// [32 slot][2 dir x 2 grp][64 cb] of 1KB chunks ([32 rows][16 cols] bf16).
// NO flags, NO store-ack, NO commit barrier: the ring is sentinel-filled
// (0xFFFF, unreachable — |h| <= 1) by hipMemsetAsync before each layer, and
// each producer thread re-sentinels its bytes of slot (s+17)%32 (16 steps =
// ~60us before that slot's data write; inter-block skew <= 1 step by the
// data-dependence). Consumers load slot s%32 and verify no 0xFFFF (packed
// u16-max reduce); retry until clean. Producers fire-and-forget.
__global__ __launch_bounds__(256, 1) void gru_layer(
    const uint16_t* __restrict__ xp,   // (T,B,3H) bf16 (bias already added)
    const uint16_t* __restrict__ U,    // (3H, H) bf16, rows: Ur | Uz | Un
    const float* __restrict__ bn,      // (H)
    char* __restrict__ hring,          // [32][4][64] * 1KB = 8 MB
    uint16_t* __restrict__ out_bf,     // (T,B,2H) bf16 or null
    float* __restrict__ out_f32,       // (T,B,2H) f32 or null
    float* __restrict__ hid)           // 2 slots of (64,1024) f32: fwd then bwd
{
  __shared__ float red[4 * 48 * 72];
  const int tid  = threadIdx.x;
  const int lane = tid & 63, wid = tid >> 6;
  const int bid  = blockIdx.x;
  const int dir  = bid >> 7;
  const int grp  = (bid >> 6) & 1;
  const int dg   = dir * 2 + grp;      // domain 0..3
  const int cb   = bid & 63;
  const int c0   = cb * 16;
  const int brow0 = grp * 32;
  const int l15 = lane & 15, l4 = lane >> 4;
  const int gm = tid >> 3;             // gate row 0..31
  const int cp = (tid & 7) * 2;        // gate col pair

  // register-resident B fragments (U weights), reused for all 256 steps
  short8v bfr[3][8];
  #pragma unroll
  for (int g = 0; g < 3; ++g)
    #pragma unroll
    for (int k32 = 0; k32 < 8; ++k32){
      int row = g * 1024 + c0 + l15;
      int k   = wid * 256 + k32 * 32 + l4 * 8;
      bfr[g][k32] = *(const short8v*)&U[(size_t)row * 1024 + k];
    }

  float hold[2] = {0.f, 0.f};
  float bnv[2] = { bn[c0 + cp], bn[c0 + cp + 1] };

  // consumer h geometry (r15-verified): chunk = wid*16 + c*2 + (l4>>1);
  // byte = chunk*1024 + (mt*16 + l15)*32 + (l4&1)*16
  const size_t hoff = (size_t)(wid * 16 + (l4 >> 1)) * 1024 + (size_t)(l4 & 1) * 16 + (size_t)l15 * 32;

  for (int s = 0; s < 256; ++s){
    const int t = dir ? (255 - s) : s;
    const size_t xb2 = ((size_t)t * 64 + brow0 + gm) * 3072 + c0 + cp;

    f32x4 acc[3][2] = {};
    unsigned pxr, pxz, pxn;
    if (s > 0){
      const char* hgbase = hring + ((size_t)((s & 31) * 4 + dg) * 64) * 1024;

      // issue xp (oldest), then all 16 h loads; single drain; verify; retry.
      XPLOAD4(pxr, &xp[xb2]);
      XPLOAD4(pxz, &xp[xb2 + 1024]);
      XPLOAD4(pxn, &xp[xb2 + 2048]);
      short8v hc[8][2];
      #pragma unroll
      for (int c = 0; c < 8; ++c)
        #pragma unroll
        for (int mt = 0; mt < 2; ++mt)
          HLOAD(hc[c][mt], hgbase + hoff + (size_t)c * 2048 + (size_t)mt * 512);
      WAITVM(0);

      int spins = 0;
      for (;;){
        // packed u16 max over all loaded h values; valid bf16 h <= 0xBF80 < 0xFFFF
        u16x8 mx = (u16x8)hc[0][0];
        #pragma unroll
        for (int c = 0; c < 8; ++c)
          #pragma unroll
          for (int mt = 0; mt < 2; ++mt)
            if (c | mt) mx = __builtin_elementwise_max(mx, (u16x8)hc[c][mt]);
        unsigned anybad = 0;
        #pragma unroll
        for (int i = 0; i < 8; ++i) anybad |= (unsigned)(mx[i] == (unsigned short)0xFFFFu);
        if (!__any((int)anybad)) break;
        __builtin_amdgcn_s_sleep(1);
        if (((++spins) & 255) == 0)
          __builtin_amdgcn_fence(__ATOMIC_ACQUIRE, "agent");   // safety valve
        #pragma unroll
        for (int c = 0; c < 8; ++c)
          #pragma unroll
          for (int mt = 0; mt < 2; ++mt)
            HLOAD(hc[c][mt], hgbase + hoff + (size_t)c * 2048 + (size_t)mt * 512);
        WAITVM(0);
      }

      // MFMA over the verified window
      #pragma unroll
      for (int kk = 0; kk < 8; ++kk)
        #pragma unroll
        for (int g = 0; g < 3; ++g)
          #pragma unroll
          for (int mt = 0; mt < 2; ++mt)
            acc[g][mt] = __builtin_amdgcn_mfma_f32_16x16x32_bf16(hc[kk][mt], bfr[g][kk], acc[g][mt], 0, 0, 0);
    } else {
      pxr = *(const unsigned*)&xp[xb2];
      pxz = *(const unsigned*)&xp[xb2 + 1024];
      pxn = *(const unsigned*)&xp[xb2 + 2048];
    }

    // partial sums to LDS (stride-72 swizzled, conflict-free writes)
    #pragma unroll
    for (int g = 0; g < 3; ++g)
      #pragma unroll
      for (int mt = 0; mt < 2; ++mt)
        *(f32x4*)&red[ridx(wid, g * 16 + l15, mt * 16 + l4 * 4)] = acc[g][mt];
    __syncthreads();                       // sync1: partials ready

    // reduce over 4 waves; thread -> (row gm, cols cp, cp+1)
    float ra[2] = {}, za[2] = {}, na[2] = {};
    #pragma unroll
    for (int w = 0; w < 4; ++w)
      #pragma unroll
      for (int j = 0; j < 2; ++j){
        ra[j] += red[ridx(w,      cp + j, gm)];
        za[j] += red[ridx(w, 16 + cp + j, gm)];
        na[j] += red[ridx(w, 32 + cp + j, gm)];
      }
    __syncthreads();                       // sync2: red reads done (WAR safe)

    unsigned hv = 0;
    float hn[2];
    #pragma unroll
    for (int j = 0; j < 2; ++j){
      float xr = bf2f((uint16_t)(pxr >> (16 * j)));
      float xz = bf2f((uint16_t)(pxz >> (16 * j)));
      float xn = bf2f((uint16_t)(pxn >> (16 * j)));
      float r = 1.f / (1.f + __expf(-(xr + ra[j])));
      float z = 1.f / (1.f + __expf(-(xz + za[j])));
      float n = tanhf(xn + r * (na[j] + bnv[j]));
      hn[j] = (1.f - z) * n + z * hold[j];
      hold[j] = hn[j];
      hv |= ((unsigned)f2bf(hn[j])) << (16 * j);
    }

    // fire-and-forget: h -> slot (s+1)%32; sentinel -> slot (s+17)%32
    {
      const size_t mybyte = (size_t)cb * 1024 + (size_t)gm * 32 + (size_t)cp * 2;
      char* hw = hring + ((size_t)(((s + 1) & 31) * 4 + dg) * 64) * 1024 + mybyte;
      HSTORE4(hw, hv);
      char* sw = hring + ((size_t)(((s + 17) & 31) * 4 + dg) * 64) * 1024 + mybyte;
      HSTORE4(sw, 0xFFFFFFFFu);
    }

    // out store (drains inside next step's WAITVM(0))
    {
      size_t obase = ((size_t)t * 64 + brow0 + gm) * 2048 + (size_t)dir * 1024 + c0 + cp;
      if (out_bf) OSTORE4(&out_bf[obase], hv);
      else {
        f32x2 ov = { hn[0], hn[1] };
        OSTORE8(&out_f32[obase], ov);
      }
      if (s == 255){
        f32x2 hvv = { hn[0], hn[1] };
        *(f32x2*)&hid[((size_t)dir * 64 + brow0 + gm) * 1024 + c0 + cp] = hvv;
      }
    }
  }
}

// ---------- host ----------
extern "C" void kernel_launch(void* const* d_in, const int* in_sizes, int n_in,
                              void* d_out, int out_size, void* d_ws, size_t ws_size,
                              hipStream_t stream) {
  const float* x   = (const float*)d_in[0];
  const float* W0  = (const float*)d_in[1];
  const float* b0  = (const float*)d_in[2];
  const float* Ur0 = (const float*)d_in[3];
  const float* Uz0 = (const float*)d_in[4];
  const float* Un0 = (const float*)d_in[5];
  const float* bn0 = (const float*)d_in[6];
  const float* W1  = (const float*)d_in[7];
  const float* b1  = (const float*)d_in[8];
  const float* Ur1 = (const float*)d_in[9];
  const float* Uz1 = (const float*)d_in[10];
  const float* Un1 = (const float*)d_in[11];
  const float* bn1 = (const float*)d_in[12];
  float* out = (float*)d_out;

  const size_t RING = (size_t)8 * 1024 * 1024;   // 32 slots x 4 domains x 64KB
  char* base = (char*)d_ws;
  char*     hring = base;
  uint16_t* xb    = (uint16_t*)(base + RING);
  uint16_t* w0b   = xb    + (size_t)16384 * 1024;
  uint16_t* u0b   = w0b   + (size_t)3072 * 1024;
  uint16_t* w1b   = u0b   + (size_t)3072 * 1024;
  uint16_t* u1b   = w1b   + (size_t)3072 * 2048;
  uint16_t* xp    = u1b   + (size_t)3072 * 1024;
  uint16_t* out0b = xp    + (size_t)16384 * 3072;

  auto cvt = [&](const float* s, uint16_t* d, size_t n){
    int n4 = (int)(n / 4);
    int grid = (n4 + 255) / 256; if (grid > 2048) grid = 2048;
    hipLaunchKernelGGL(cvt_f32_bf16, dim3(grid), dim3(256), 0, stream, s, d, n4);
  };
  // sentinel-fill the ring for layer 0 (in-graph, replayed each call)
  hipMemsetAsync(hring, 0xFF, RING, stream);

  cvt(x,   xb,  (size_t)16384 * 1024);
  cvt(W0,  w0b, (size_t)3072 * 1024);
  cvt(Ur0, u0b + 0 * (size_t)1024 * 1024, (size_t)1024 * 1024);
  cvt(Uz0, u0b + 1 * (size_t)1024 * 1024, (size_t)1024 * 1024);
  cvt(Un0, u0b + 2 * (size_t)1024 * 1024, (size_t)1024 * 1024);
  cvt(W1,  w1b, (size_t)3072 * 2048);
  cvt(Ur1, u1b + 0 * (size_t)1024 * 1024, (size_t)1024 * 1024);
  cvt(Uz1, u1b + 1 * (size_t)1024 * 1024, (size_t)1024 * 1024);
  cvt(Un1, u1b + 2 * (size_t)1024 * 1024, (size_t)1024 * 1024);

  // layer 0: xp0 = x @ W0^T + b0
  hipLaunchKernelGGL(gemm_bt_bias, dim3(24, 128), dim3(256), 0, stream,
                     xb, w0b, b0, xp, 16384, 3072, 1024);
  // layer 0 recurrence -> out0b (bf16), hidden slots 0,1
  hipLaunchKernelGGL(gru_layer, dim3(256), dim3(256), 0, stream,
                     xp, u0b, bn0, hring,
                     out0b, (float*)nullptr,
                     out + (size_t)33554432);
  // re-sentinel the ring for layer 1 (stream-ordered after layer 0)
  hipMemsetAsync(hring, 0xFF, RING, stream);
  // layer 1: xp1 = out0 @ W1^T + b1
  hipLaunchKernelGGL(gemm_bt_bias, dim3(24, 128), dim3(256), 0, stream,
                     out0b, w1b, b1, xp, 16384, 3072, 2048);
  // layer 1 recurrence -> d_out (f32), hidden slots 2,3
  hipLaunchKernelGGL(gru_layer, dim3(256), dim3(256), 0, stream,
                     xp, u1b, bn1, hring,
                     (uint16_t*)nullptr, out,
                     out + (size_t)33554432 + (size_t)2 * 64 * 1024);
}

// Round 19
// 2115.781 us; speedup vs baseline: 1.7924x; 1.0712x over previous
//
#include <hip/hip_runtime.h>
#include <stdint.h>

// ---------- types ----------
typedef short short8v __attribute__((ext_vector_type(8)));
typedef unsigned short u16x8 __attribute__((ext_vector_type(8)));
typedef float f32x4  __attribute__((ext_vector_type(4)));
typedef unsigned long long u64;

__device__ inline uint16_t f2bf(float f){
  uint32_t u = __float_as_uint(f);
  uint32_t r = (u + 0x7fffu + ((u >> 16) & 1u)) >> 16;
  return (uint16_t)r;
}
__device__ inline float bf2f(uint16_t h){
  return __uint_as_float(((uint32_t)h) << 16);
}

// ---------- f32 -> bf16 conversion (vectorized) ----------
__global__ void cvt_f32_bf16(const float* __restrict__ src, uint16_t* __restrict__ dst, int n4){
  int i = blockIdx.x * blockDim.x + threadIdx.x;
  int stride = gridDim.x * blockDim.x;
  for (; i < n4; i += stride){
    float4 v = ((const float4*)src)[i];
    uint64_t p = (uint64_t)f2bf(v.x)
               | ((uint64_t)f2bf(v.y) << 16)
               | ((uint64_t)f2bf(v.z) << 32)
               | ((uint64_t)f2bf(v.w) << 48);
    ((uint64_t*)dst)[i] = p;
  }
}

// ---------- bf16 GEMM: C[m,n] = sum_k A[m,k] * Bw[n,k] + bias[n]  (C bf16) ----------
#define GL2LDS(g, l) __builtin_amdgcn_global_load_lds((const __attribute__((address_space(1))) unsigned int*)(g), (__attribute__((address_space(3))) unsigned int*)(l), 16, 0, 0)

__global__ __launch_bounds__(256) void gemm_bt_bias(
    const uint16_t* __restrict__ A, const uint16_t* __restrict__ Bw,
    const float* __restrict__ bias, uint16_t* __restrict__ C,
    int M, int N, int K)
{
  __shared__ uint16_t As[128 * 64];
  __shared__ uint16_t Bs[128 * 64];
  const int tid  = threadIdx.x;
  const int lane = tid & 63, wid = tid >> 6;
  const int n0 = blockIdx.x * 128, m0 = blockIdx.y * 128;
  const int wrow = (wid & 1) * 64, wcol = (wid >> 1) * 64;
  const int l15 = lane & 15, l4 = lane >> 4;
  const int srow = lane >> 3, scol = (lane & 7) * 8;
  const size_t Ks = (size_t)K;

  f32x4 acc[4][4] = {};

  for (int kt = 0; kt < K; kt += 64){
    __syncthreads();
    const uint16_t* gA = A  + (size_t)m0 * Ks + kt;
    const uint16_t* gB = Bw + (size_t)n0 * Ks + kt;
    #pragma unroll
    for (int i = 0; i < 4; ++i){
      int rb = wid * 32 + i * 8;
      GL2LDS(gA + (size_t)(rb + srow) * Ks + scol, &As[rb * 64]);
      GL2LDS(gB + (size_t)(rb + srow) * Ks + scol, &Bs[rb * 64]);
    }
    __syncthreads();
    #pragma unroll
    for (int kk = 0; kk < 2; ++kk){
      short8v a[4], b[4];
      int koff = kk * 32 + l4 * 8;
      #pragma unroll
      for (int mt = 0; mt < 4; ++mt) a[mt] = *(const short8v*)&As[(wrow + mt*16 + l15) * 64 + koff];
      #pragma unroll
      for (int nt = 0; nt < 4; ++nt) b[nt] = *(const short8v*)&Bs[(wcol + nt*16 + l15) * 64 + koff];
      #pragma unroll
      for (int mt = 0; mt < 4; ++mt)
        #pragma unroll
        for (int nt = 0; nt < 4; ++nt)
          acc[mt][nt] = __builtin_amdgcn_mfma_f32_16x16x32_bf16(a[mt], b[nt], acc[mt][nt], 0, 0, 0);
    }
  }
  #pragma unroll
  for (int mt = 0; mt < 4; ++mt)
    #pragma unroll
    for (int nt = 0; nt < 4; ++nt){
      int col = n0 + wcol + nt * 16 + l15;
      float bv = bias[col];
      int rbase = m0 + wrow + mt * 16 + l4 * 4;
      #pragma unroll
      for (int j = 0; j < 4; ++j)
        C[(size_t)(rbase + j) * (size_t)N + col] = f2bf(acc[mt][nt][j] + bv);
    }
}

// LDS reduce index, stride 40 f32, 8 waves (same verified XOR family:
// f32x4 writes conflict-free; max m^((c&7)<<2) = 31 < 40).
__device__ inline int ridx8(int w, int c, int m){
  return (w * 48 + c) * 40 + (m ^ ((c & 7) << 2));
}

// 16B MALL-direct load (bypass L1+L2) — proven r4/r10
#define HLOAD(dst, addr) \
  asm volatile("global_load_dwordx4 %0, %1, off sc0 sc1" : "=v"(dst) : "v"(addr) : "memory")
// plain cached 2B load (xp)
#define XPLOAD2(dst, addr) \
  asm volatile("global_load_ushort %0, %1, off" : "=v"(dst) : "v"(addr) : "memory")
// write-through 2B store (h / sentinel), fire-and-forget
#define HSTORE2(addr, val) \
  asm volatile("global_store_short %0, %1, off sc0 sc1" :: "v"(addr), "v"(val) : "memory")
#define OSTORE2(addr, val) \
  asm volatile("global_store_short %0, %1, off nt" :: "v"(addr), "v"(val) : "memory")
#define OSTORE4(addr, val) \
  asm volatile("global_store_dword %0, %1, off nt" :: "v"(addr), "v"(val) : "memory")
#define WAITVM(n) do { asm volatile("s_waitcnt vmcnt(" #n ")" ::: "memory"); \
                       __builtin_amdgcn_sched_barrier(0); } while (0)

// ---------- persistent bidirectional GRU layer, self-certifying h ring ----------
// r18 protocol byte-identical (32-slot sentinel ring, fire-and-forget h +
// sentinel re-arm 16 steps ahead, data-verify via packed u16-max, retry loop).
// CHANGE: 512-thread blocks, K split across 8 waves (128 cols each) — 8
// waves/CU so retry RTTs of some waves hide under others' loads/MFMA.
// grid = 256 blocks: dir = bid>>7, grp = (bid>>6)&1 (32 rows), cb = bid&63.
__global__ __launch_bounds__(512, 1) void gru_layer(
    const uint16_t* __restrict__ xp,   // (T,B,3H) bf16 (bias already added)
    const uint16_t* __restrict__ U,    // (3H, H) bf16, rows: Ur | Uz | Un
    const float* __restrict__ bn,      // (H)
    char* __restrict__ hring,          // [32 slot][4 dom][64 cb] * 1KB = 8 MB
    uint16_t* __restrict__ out_bf,     // (T,B,2H) bf16 or null
    float* __restrict__ out_f32,       // (T,B,2H) f32 or null
    float* __restrict__ hid)           // 2 slots of (64,1024) f32: fwd then bwd
{
  __shared__ float red[8 * 48 * 40];   // 61440 B
  const int tid  = threadIdx.x;
  const int lane = tid & 63, wid = tid >> 6;   // 8 waves
  const int bid  = blockIdx.x;
  const int dir  = bid >> 7;
  const int grp  = (bid >> 6) & 1;
  const int dg   = dir * 2 + grp;      // domain 0..3
  const int cb   = bid & 63;
  const int c0   = cb * 16;
  const int brow0 = grp * 32;
  const int l15 = lane & 15, l4 = lane >> 4;
  const int gm = tid >> 4;             // gate row 0..31
  const int c16 = tid & 15;            // gate col 0..15

  // register-resident B fragments (U weights): wave wid owns k = wid*128..+127
  short8v bfr[3][4];
  #pragma unroll
  for (int g = 0; g < 3; ++g)
    #pragma unroll
    for (int kk = 0; kk < 4; ++kk){
      int row = g * 1024 + c0 + l15;
      int k   = wid * 128 + kk * 32 + l4 * 8;
      bfr[g][kk] = *(const short8v*)&U[(size_t)row * 1024 + k];
    }

  float hold = 0.f;
  const float bnv = bn[c0 + c16];

  // consumer h geometry (r18-verified family): chunk = wid*8 + kk*2 + (l4>>1);
  // byte = chunk*1024 + (l4&1)*16 + l15*32 ; mt selects 16-row half (+512B)
  const size_t hoff = (size_t)(wid * 8 + (l4 >> 1)) * 1024 + (size_t)(l4 & 1) * 16 + (size_t)l15 * 32;

  for (int s = 0; s < 256; ++s){
    const int t = dir ? (255 - s) : s;
    const size_t xb2 = ((size_t)t * 64 + brow0 + gm) * 3072 + c0 + c16;

    f32x4 acc[3][2] = {};
    unsigned pxr, pxz, pxn;
    if (s > 0){
      const char* hgbase = hring + ((size_t)((s & 31) * 4 + dg) * 64) * 1024;

      // issue xp (oldest), then this wave's 8 h loads; drain; verify; retry.
      XPLOAD2(pxr, &xp[xb2]);
      XPLOAD2(pxz, &xp[xb2 + 1024]);
      XPLOAD2(pxn, &xp[xb2 + 2048]);
      short8v hc[4][2];
      #pragma unroll
      for (int kk = 0; kk < 4; ++kk)
        #pragma unroll
        for (int mt = 0; mt < 2; ++mt)
          HLOAD(hc[kk][mt], hgbase + hoff + (size_t)kk * 2048 + (size_t)mt * 512);
      WAITVM(0);

      int spins = 0;
      for (;;){
        // packed u16 max; valid bf16 |h|<=1 -> max 0xBF80 < 0xFFFF sentinel
        u16x8 mx = (u16x8)hc[0][0];
        #pragma unroll
        for (int kk = 0; kk < 4; ++kk)
          #pragma unroll
          for (int mt = 0; mt < 2; ++mt)
            if (kk | mt) mx = __builtin_elementwise_max(mx, (u16x8)hc[kk][mt]);
        unsigned anybad = 0;
        #pragma unroll
        for (int i = 0; i < 8; ++i) anybad |= (unsigned)(mx[i] == (unsigned short)0xFFFFu);
        if (!__any((int)anybad)) break;
        __builtin_amdgcn_s_sleep(1);
        if (((++spins) & 255) == 0)
          __builtin_amdgcn_fence(__ATOMIC_ACQUIRE, "agent");   // safety valve
        #pragma unroll
        for (int kk = 0; kk < 4; ++kk)
          #pragma unroll
          for (int mt = 0; mt < 2; ++mt)
            HLOAD(hc[kk][mt], hgbase + hoff + (size_t)kk * 2048 + (size_t)mt * 512);
        WAITVM(0);
      }

      // MFMA over the verified window (24 MFMAs/wave)
      #pragma unroll
      for (int kk = 0; kk < 4; ++kk)
        #pragma unroll
        for (int g = 0; g < 3; ++g)
          #pragma unroll
          for (int mt = 0; mt < 2; ++mt)
            acc[g][mt] = __builtin_amdgcn_mfma_f32_16x16x32_bf16(hc[kk][mt], bfr[g][kk], acc[g][mt], 0, 0, 0);
    } else {
      pxr = xp[xb2];
      pxz = xp[xb2 + 1024];
      pxn = xp[xb2 + 2048];
    }

    // partial sums to LDS (8-wave stride-40 swizzle, conflict-free writes)
    #pragma unroll
    for (int g = 0; g < 3; ++g)
      #pragma unroll
      for (int mt = 0; mt < 2; ++mt)
        *(f32x4*)&red[ridx8(wid, g * 16 + l15, mt * 16 + l4 * 4)] = acc[g][mt];
    __syncthreads();                       // sync1: partials ready

    // reduce over 8 waves; thread -> (row gm, col c16)
    float ra = 0.f, za = 0.f, na = 0.f;
    #pragma unroll
    for (int w = 0; w < 8; ++w){
      ra += red[ridx8(w,      c16, gm)];
      za += red[ridx8(w, 16 + c16, gm)];
      na += red[ridx8(w, 32 + c16, gm)];
    }
    __syncthreads();                       // sync2: red reads done (WAR safe)

    WAITVM(0);                             // xp retired (s==0 path too)
    float xr = bf2f((uint16_t)pxr);
    float xz = bf2f((uint16_t)pxz);
    float xn = bf2f((uint16_t)pxn);
    float r = 1.f / (1.f + __expf(-(xr + ra)));
    float z = 1.f / (1.f + __expf(-(xz + za)));
    float n = tanhf(xn + r * (na + bnv));
    float hn = (1.f - z) * n + z * hold;
    hold = hn;
    unsigned hv = f2bf(hn);

    // fire-and-forget: h -> slot (s+1)%32; sentinel re-arm -> slot (s+17)%32
    {
      const size_t mybyte = (size_t)cb * 1024 + (size_t)gm * 32 + (size_t)c16 * 2;
      char* hw = hring + ((size_t)(((s + 1) & 31) * 4 + dg) * 64) * 1024 + mybyte;
      HSTORE2(hw, hv);
      char* sw = hring + ((size_t)(((s + 17) & 31) * 4 + dg) * 64) * 1024 + mybyte;
      HSTORE2(sw, 0xFFFFu);
    }

    // out store (drains inside next step's WAITVM(0))
    {
      size_t obase = ((size_t)t * 64 + brow0 + gm) * 2048 + (size_t)dir * 1024 + c0 + c16;
      if (out_bf) OSTORE2(&out_bf[obase], hv);
      else        OSTORE4(&out_f32[obase], __float_as_uint(hn));
      if (s == 255)
        hid[((size_t)dir * 64 + brow0 + gm) * 1024 + c0 + c16] = hn;
    }
  }
}

// ---------- host ----------
extern "C" void kernel_launch(void* const* d_in, const int* in_sizes, int n_in,
                              void* d_out, int out_size, void* d_ws, size_t ws_size,
                              hipStream_t stream) {
  const float* x   = (const float*)d_in[0];
  const float* W0  = (const float*)d_in[1];
  const float* b0  = (const float*)d_in[2];
  const float* Ur0 = (const float*)d_in[3];
  const float* Uz0 = (const float*)d_in[4];
  const float* Un0 = (const float*)d_in[5];
  const float* bn0 = (const float*)d_in[6];
  const float* W1  = (const float*)d_in[7];
  const float* b1  = (const float*)d_in[8];
  const float* Ur1 = (const float*)d_in[9];
  const float* Uz1 = (const float*)d_in[10];
  const float* Un1 = (const float*)d_in[11];
  const float* bn1 = (const float*)d_in[12];
  float* out = (float*)d_out;

  const size_t RING = (size_t)8 * 1024 * 1024;   // 32 slots x 4 domains x 64KB
  char* base = (char*)d_ws;
  char*     hring = base;
  uint16_t* xb    = (uint16_t*)(base + RING);
  uint16_t* w0b   = xb    + (size_t)16384 * 1024;
  uint16_t* u0b   = w0b   + (size_t)3072 * 1024;
  uint16_t* w1b   = u0b   + (size_t)3072 * 1024;
  uint16_t* u1b   = w1b   + (size_t)3072 * 2048;
  uint16_t* xp    = u1b   + (size_t)3072 * 1024;
  uint16_t* out0b = xp    + (size_t)16384 * 3072;

  auto cvt = [&](const float* s, uint16_t* d, size_t n){
    int n4 = (int)(n / 4);
    int grid = (n4 + 255) / 256; if (grid > 2048) grid = 2048;
    hipLaunchKernelGGL(cvt_f32_bf16, dim3(grid), dim3(256), 0, stream, s, d, n4);
  };
  // sentinel-fill the ring for layer 0 (in-graph, replayed each call)
  hipMemsetAsync(hring, 0xFF, RING, stream);

  cvt(x,   xb,  (size_t)16384 * 1024);
  cvt(W0,  w0b, (size_t)3072 * 1024);
  cvt(Ur0, u0b + 0 * (size_t)1024 * 1024, (size_t)1024 * 1024);
  cvt(Uz0, u0b + 1 * (size_t)1024 * 1024, (size_t)1024 * 1024);
  cvt(Un0, u0b + 2 * (size_t)1024 * 1024, (size_t)1024 * 1024);
  cvt(W1,  w1b, (size_t)3072 * 2048);
  cvt(Ur1, u1b + 0 * (size_t)1024 * 1024, (size_t)1024 * 1024);
  cvt(Uz1, u1b + 1 * (size_t)1024 * 1024, (size_t)1024 * 1024);
  cvt(Un1, u1b + 2 * (size_t)1024 * 1024, (size_t)1024 * 1024);

  // layer 0: xp0 = x @ W0^T + b0
  hipLaunchKernelGGL(gemm_bt_bias, dim3(24, 128), dim3(256), 0, stream,
                     xb, w0b, b0, xp, 16384, 3072, 1024);
  // layer 0 recurrence -> out0b (bf16), hidden slots 0,1
  hipLaunchKernelGGL(gru_layer, dim3(256), dim3(512), 0, stream,
                     xp, u0b, bn0, hring,
                     out0b, (float*)nullptr,
                     out + (size_t)33554432);
  // re-sentinel the ring for layer 1 (stream-ordered after layer 0)
  hipMemsetAsync(hring, 0xFF, RING, stream);
  // layer 1: xp1 = out0 @ W1^T + b1
  hipLaunchKernelGGL(gemm_bt_bias, dim3(24, 128), dim3(256), 0, stream,
                     out0b, w1b, b1, xp, 16384, 3072, 2048);
  // layer 1 recurrence -> d_out (f32), hidden slots 2,3
  hipLaunchKernelGGL(gru_layer, dim3(256), dim3(512), 0, stream,
                     xp, u1b, bn1, hring,
                     (uint16_t*)nullptr, out,
                     out + (size_t)33554432 + (size_t)2 * 64 * 1024);
}